// Round 12
// baseline (246.514 us; speedup 1.0000x reference)
//
#include <hip/hip_runtime.h>

// Problem constants
#define EMB  4096
#define DH   128      // QKV_DIM
#define NH   32       // N_HEADS
#define NTOK 16384    // B*S
#define NCOL 384      // qs | k | v columns

// Fused tile: 32(M) x 384(N=all) block, BK=64, 6 waves, wave tile 32x64 (acc 2x4)
#define BM 32
#define BK 64

typedef __attribute__((ext_vector_type(8))) short short8;
typedef __attribute__((ext_vector_type(4))) short short4_t;
typedef __attribute__((ext_vector_type(4))) float f32x4;

// f32 pair -> packed bf16x2, RNE (hardware cvt)
static __device__ __forceinline__ unsigned int cvt2(float a, float b) {
    unsigned int r;
    asm volatile("v_cvt_pk_bf16_f32 %0, %1, %2" : "=v"(r) : "v"(a), "v"(b));
    return r;
}
// scalar f32 -> bf16 bits, RNE (prep_w only)
static __device__ __forceinline__ unsigned short f2bf(float f) {
    unsigned int u = __builtin_bit_cast(unsigned int, f);
    u += 0x7fffu + ((u >> 16) & 1u);
    return (unsigned short)(u >> 16);
}

// ---------------------------------------------------------------------------
// Kernel 1: build W3F — combined weights W3[384][4096] (bf16) in MFMA
// FRAGMENT-LINEAR order (proven R10): for panel p (=n>>6), k-tile kt (=D>>6),
// chunk (kh*4+j), lane, the 16 B at
//   byte = p*524288 + kt*8192 + (kh*4+j)*1024 + lane*16
// hold B[n=j*16+lmod][D=kt*64+kh*32+lgrp*8+e] — one lane's B-fragment.
// Also bias[384].
// ---------------------------------------------------------------------------
__global__ void prep_w(const float* __restrict__ Wq, const float* __restrict__ bq,
                       const float* __restrict__ Wk, const float* __restrict__ bk,
                       const float* __restrict__ Wv, const float* __restrict__ bv,
                       unsigned short* __restrict__ W3F, float* __restrict__ bias) {
    const int tid = blockIdx.x * 256 + threadIdx.x;   // [0, 384*512)
    const int n  = tid >> 9;          // output column [0,384)
    const int ck = tid & 511;         // 8-element chunk of the 4096 K dim
    const int D0 = ck * 8;

    float v[8];
    if (n < DH) {
#pragma unroll
        for (int e = 0; e < 8; ++e) {
            const float4* p = (const float4*)(Wq + (size_t)(D0 + e) * (DH * NH) + n * NH);
            float s = 0.f;
#pragma unroll
            for (int i = 0; i < 8; ++i) { float4 q = p[i]; s += (q.x + q.y) + (q.z + q.w); }
            v[e] = s;
        }
    } else if (n < 2 * DH) {
#pragma unroll
        for (int e = 0; e < 8; ++e) v[e] = Wk[(size_t)(D0 + e) * DH + (n - DH)];
    } else {
#pragma unroll
        for (int e = 0; e < 8; ++e) v[e] = Wv[(size_t)(D0 + e) * DH + (n - 2 * DH)];
    }

    union { short8 s; unsigned int u[4]; } pk;
#pragma unroll
    for (int j = 0; j < 4; ++j)
        pk.u[j] = (unsigned int)f2bf(v[2 * j]) | ((unsigned int)f2bf(v[2 * j + 1]) << 16);

    const int p    = n >> 6, r = n & 63;
    const int jfr  = r >> 4, lmod = r & 15;
    const int kt   = ck >> 3;
    const int kh   = (ck >> 2) & 1;
    const int lgrp = ck & 3;
    const int lane = lgrp * 16 + lmod;
    char* dst = (char*)W3F + (size_t)p * 524288 + (size_t)kt * 8192
              + (kh * 4 + jfr) * 1024 + lane * 16;
    *(short8*)dst = pk.s;

    if (ck == 0) {
        float b;
        if (n < DH) {
            float s = 0.f;
#pragma unroll
            for (int h = 0; h < NH; ++h) s += bq[n * NH + h];
            b = s;
        } else if (n < 2 * DH) {
            b = bk[n - DH];
        } else {
            b = bv[n - 2 * DH];
        }
        bias[n] = b;
    }
}

// ---------------------------------------------------------------------------
// Kernel 2 (FUSED): per 32-token stripe: qkv = x @ W3 + bias (bf16 MFMA),
// then in-block rank-1 softmax + broadcast out-write. No qkv intermediate.
// 6 waves (384 thr); wave w owns output cols [w*64,(w+1)*64); acc 2x4.
// B global->VGPR from fragment-linear W3F (L2-resident). A via 4-KB LDS tile
// with the proven XOR-chunk swizzle. Epilogue softmax broadcast is PURE
// REGISTER __shfl (no LDS write->cross-lane-read edge — fixed the R11 replay
// race). 52 KB LDS -> 2 blocks/CU so epilogues overlap other blocks' gemm.
// ---------------------------------------------------------------------------
__global__ __launch_bounds__(384) void fused_mqa(const float* __restrict__ X,
                         const unsigned short* __restrict__ W3F,
                         const float* __restrict__ bias,
                         float* __restrict__ out) {
    __shared__ __align__(16) unsigned short Asm[BM * BK];   //  4 KB
    __shared__ float qsm[BM * NCOL];                        // 48 KB

    // XCD-bijective remap over 512 blocks (512 % 8 == 0, 64 per XCD)
    const int bid  = blockIdx.x;
    const int wkid = (bid & 7) * 64 + (bid >> 3);
    const int m0   = wkid * BM;
    const int nt   = EMB / BK;                // 64

    const int t = threadIdx.x, lane = t & 63, w = t >> 6;   // w in {0..5}
    const int lmod = lane & 15, lgrp = lane >> 4;

    f32x4 acc[2][4] = {};

    // A staging (waves 0-3): wave w covers rows [w*8, w*8+8); instr i covers
    // rows w*8 + i*4 + (lane>>4), 16 B at (lane&15)*16 of the row's 256-B span.
    const int arow4 = lane >> 4;
    const float* xp = X + (size_t)(m0 + w * 8 + arow4) * EMB + (lane & 15) * 4;
    const int acs = (lane & 15) >> 1;
    const int ah4 = (lane & 1) * 4;

    // B source: wave w consumes panel w, fragment-linear
    const char* bsrc = (const char*)W3F + (size_t)w * 524288 + lane * 16;

    float4 av[2];

#define LOAD_AV(T) do { \
    _Pragma("unroll") \
    for (int i = 0; i < 2; ++i) av[i] = *(const float4*)(xp + (T) * BK + i * 4 * EMB); \
} while (0)

#define WRITE_A() do { \
    _Pragma("unroll") \
    for (int idx = 0; idx < 2; ++idx) { \
        const int rl = w * 8 + idx * 4 + arow4; \
        union { short4_t s; unsigned int u[2]; } pk; \
        pk.u[0] = cvt2(av[idx].x, av[idx].y); \
        pk.u[1] = cvt2(av[idx].z, av[idx].w); \
        *(short4_t*)(&Asm[rl * BK + ((acs ^ (rl & 7)) << 3) + ah4]) = pk.s; \
    } \
} while (0)

    // prologue
    if (w < 4) LOAD_AV(0);

    for (int tt = 0; tt < nt; ++tt) {
        __syncthreads();                      // readers of previous tile done
        if (w < 4) WRITE_A();                 // av(tile tt)
        __syncthreads();                      // tile resident
        if (w < 4 && tt + 1 < nt) LOAD_AV(tt + 1);

        const char* bt = bsrc + (size_t)tt * 8192;
#pragma unroll
        for (int kh = 0; kh < 2; ++kh) {
            short8 af[2], bf[4];
#pragma unroll
            for (int j = 0; j < 4; ++j)
                bf[j] = *(const short8*)(bt + (kh * 4 + j) * 1024);   // global, L2
            const int cs = ((kh * 4 + lgrp) ^ (lmod & 7)) * 8;
#pragma unroll
            for (int i = 0; i < 2; ++i)
                af[i] = *(const short8*)(&Asm[(i * 16 + lmod) * BK + cs]);
#pragma unroll
            for (int i = 0; i < 2; ++i)
#pragma unroll
                for (int j = 0; j < 4; ++j)
                    acc[i][j] = __builtin_amdgcn_mfma_f32_16x16x32_bf16(af[i], bf[j], acc[i][j], 0, 0, 0);
        }
    }

    // ---- epilogue 1: acc + bias -> qsm[32][384] ----
    // C/D layout: col = lane&15, row = (lane>>4)*4 + reg
#pragma unroll
    for (int j = 0; j < 4; ++j) {
        const int col = w * 64 + j * 16 + lmod;
        const float bj = bias[col];
#pragma unroll
        for (int i = 0; i < 2; ++i) {
            const int row = i * 16 + (lgrp << 2);
#pragma unroll
            for (int r = 0; r < 4; ++r)
                qsm[(row + r) * NCOL + col] = acc[i][j][r] + bj;
        }
    }
    __syncthreads();

    // ---- epilogue 2: per-token rank-1 softmax + register-shfl broadcast ----
    const float c = 0.088388347648318447f * 1.4426950408889634f; // scale*log2(e)
    for (int tok = w; tok < BM; tok += 6) {
        const float* row = &qsm[tok * NCOL];
        const float q0  = row[lane],       q1  = row[64 + lane];
        const float kk0 = row[128 + lane], kk1 = row[192 + lane];

        float lmax = fmaxf(kk0, kk1), lmin = fminf(kk0, kk1);
#pragma unroll
        for (int off = 32; off; off >>= 1) {
            lmax = fmaxf(lmax, __shfl_xor(lmax, off));
            lmin = fminf(lmin, __shfl_xor(lmin, off));
        }

        const float a0 = q0 * c, a1 = q1 * c;
        const float m0v = (a0 >= 0.f) ? a0 * lmax : a0 * lmin;
        const float m1v = (a1 >= 0.f) ? a1 * lmax : a1 * lmin;

        float s00 = 0.f, s01 = 0.f, s10 = 0.f, s11 = 0.f;
#pragma unroll 4
        for (int e = 0; e < DH; ++e) {
            const float kv = row[128 + e];    // broadcast LDS read
            const float vv = row[256 + e];
            const float p0 = exp2f(fmaf(a0, kv, -m0v));
            const float p1 = exp2f(fmaf(a1, kv, -m1v));
            s00 += p0;  s01 = fmaf(p0, vv, s01);
            s10 += p1;  s11 = fmaf(p1, vv, s11);
        }
        const float o0 = s01 / s00;           // o[d] for d = lane      (0..63)
        const float o1 = s11 / s10;           // o[d] for d = 64 + lane

        float* orow = out + (size_t)(m0 + tok) * (DH * NH);
#pragma unroll
        for (int it = 0; it < 16; ++it) {
            const int idx = it * 64 + lane;              // float4 index in row
            const int src = (it & 7) * 8 + (lane >> 3);  // d & 63
            const float val = (it < 8) ? __shfl(o0, src) : __shfl(o1, src);
            float4 f4; f4.x = val; f4.y = val; f4.z = val; f4.w = val;
            *(float4*)(orow + idx * 4) = f4;
        }
    }
#undef LOAD_AV
#undef WRITE_A
}

// ---------------------------------------------------------------------------
extern "C" void kernel_launch(void* const* d_in, const int* in_sizes, int n_in,
                              void* d_out, int out_size, void* d_ws, size_t ws_size,
                              hipStream_t stream) {
    const float* x  = (const float*)d_in[0];
    const float* Wq = (const float*)d_in[1];
    const float* bq = (const float*)d_in[2];
    const float* Wk = (const float*)d_in[3];
    const float* bk = (const float*)d_in[4];
    const float* Wv = (const float*)d_in[5];
    const float* bv = (const float*)d_in[6];
    float* out = (float*)d_out;

    char* ws = (char*)d_ws;
    unsigned short* W3F = (unsigned short*)ws;       // 6*524288 = 3,145,728 B
    float* bias = (float*)(ws + 3145728);            // 1,536 B

    prep_w<<<(NCOL * 512) / 256, 256, 0, stream>>>(Wq, bq, Wk, bk, Wv, bv, W3F, bias);
    fused_mqa<<<NTOK / BM, 384, 0, stream>>>(x, W3F, bias, out);
}